// Round 17
// baseline (163.265 us; speedup 1.0000x reference)
//
#include <hip/hip_runtime.h>
#include <hip/hip_bf16.h>

// ---------------------------------------------------------------------------
// BlockRC2: PRM (3 dilated stride-2 convs + GELU) -> LN1 -> kqv ->
// performer attention -> proj+skip -> LN2 -> MLP -> skip.
// Round 17: conv LDS halved again via 4x16-channel phases (13056 B -> 8
// blocks/CU, 32 waves, was 26112 B -> 41% occupancy). r11 precedent: each
// LDS halving raised occupancy and cut time; r16 confirmed stores/epilogue
// neutral. Single-delta from proven conv6: same block map, weights, swizzle
// family (key (i>>1)&3 for 64B rows), epilogue, and tail.
// ---------------------------------------------------------------------------

#define TOK 4096
#define NB  32

typedef __attribute__((ext_vector_type(8)))  short short8;
typedef __attribute__((ext_vector_type(4)))  short short4v;
typedef __attribute__((ext_vector_type(16))) float f32x16;

// gelu(x) = x * sigmoid(x*(1.5957691216 + 0.0713548162 x^2)), max err ~3e-4.
__device__ __forceinline__ float gelu_fast(float v) {
    float u = v * fmaf(0.0713548162f, v * v, 1.5957691216f);
    float e = __expf(-u);
    return v * __builtin_amdgcn_rcpf(1.f + e);
}

__device__ __forceinline__ short f2bf(float f) {
    __hip_bfloat16 h = __float2bfloat16(f);   // RNE; HW cvt on gfx950
    return *reinterpret_cast<short*>(&h);
}

__device__ __forceinline__ float bf2f(short s) {
    union { unsigned u; float f; } x;
    x.u = ((unsigned)(unsigned short)s) << 16;
    return x.f;
}

// ---------------------------------------------------------------------------
// Prep. MFMA-native layouts: frag element for lane (cl,g), reg j is
// W[col=cl][k = ks*16 + g*8 + j]  ->  stored at ((ks*2+g)*NCOL + col)*8 + j.
// ---------------------------------------------------------------------------
__global__ __launch_bounds__(256) void k_prep(
        const float* __restrict__ cw, const float* __restrict__ kw,
        const float* __restrict__ pw, const float* __restrict__ w1,
        const float* __restrict__ w2m, const float* __restrict__ wperf,
        short* __restrict__ w2c, short* __restrict__ kwbf,
        short* __restrict__ pTbf, short* __restrict__ w1bf,
        short* __restrict__ w2bf, short* __restrict__ wpbf) {
    int idx = blockIdx.x * 256 + threadIdx.x;
    if (idx < 110592) {
        int c = idx & 63;
        int t = idx >> 6;
        int e = t & 63;
        int tap = t >> 6;
        int kwi = tap % 3, t2 = tap / 3;
        int r = t2 % 3, brr = t2 / 3;
        float v = cw[(((brr * 64 + e) * 64 + c) * 3 + r) * 3 + kwi];
        int dst = ((((brr * 9 + r * 3 + kwi) * 4 + (c >> 4)) * 2 + ((c >> 3) & 1)) * 64 + e) * 8 + (c & 7);
        w2c[dst] = f2bf(v);
    } else if (idx < 147456) {
        int i2 = idx - 110592;
        int o = i2 / 192, i = i2 % 192;
        int dst = (((i >> 4) * 2 + ((i >> 3) & 1)) * 192 + o) * 8 + (i & 7);
        kwbf[dst] = f2bf(kw[i * 192 + o]);
    } else if (idx < 151552) {
        int i2 = idx - 147456;
        int o = i2 >> 6, d = i2 & 63;
        int dst = (((d >> 4) * 2 + ((d >> 3) & 1)) * 64 + o) * 8 + (d & 7);
        pTbf[dst] = f2bf(pw[d * 64 + o]);
    } else if (idx < 155648) {
        int i2 = idx - 151552;
        int i = i2 >> 6, jd = i2 & 63;
        int dst = (((jd >> 4) * 2 + ((jd >> 3) & 1)) * 64 + i) * 8 + (jd & 7);
        w1bf[dst] = f2bf(w1[jd * 64 + i]);
    } else if (idx < 159744) {
        int i2 = idx - 155648;
        int o = i2 >> 6, i = i2 & 63;
        int dst = (((i >> 4) * 2 + ((i >> 3) & 1)) * 64 + o) * 8 + (i & 7);
        w2bf[dst] = f2bf(w2m[i * 64 + o]);
    } else if (idx < 161792) {
        int i2 = idx - 159744;
        int m = i2 >> 6, d = i2 & 63;       // w_perf [m=32][d=64]
        int dst = (((d >> 4) * 2 + ((d >> 3) & 1)) * 32 + m) * 8 + (d & 7);
        wpbf[dst] = f2bf(wperf[m * 64 + d]);
    }
}

// ---------------------------------------------------------------------------
// Conv via MFMA, 4x16-channel phases. LDS sA[r=3][i=68][4 slot x 16B]
// = 13056 B -> 8 blocks/CU (thread cap). iw4 = iw+4; i = iw4>>1, p = iw4&1.
// slot = (p*2 + c8) ^ ((i>>1)&3) on BOTH write and read. Borders (i in
// {0,1,66,67}) zeroed once; staging writes only i in [2,65].
// Phase ph: stage c in [16ph,16ph+16), barrier, 9 MFMA (ks=ph), barrier.
// ---------------------------------------------------------------------------
__global__ __launch_bounds__(256) void k_conv9(
        const float* __restrict__ x, const short* __restrict__ w2c,
        const float* __restrict__ cb, short* __restrict__ tokens) {
    const int wg  = blockIdx.x;
    const int swz_id = (wg & 7) * 768 + (wg >> 3);   // 6144 = 8*768, bijective
    const int b   = swz_id / 192;
    const int rem = swz_id - b * 192;
    const int oh  = rem / 3;
    const int br  = rem - oh * 3;
    const int d   = br + 1;
    const int tid = threadIdx.x;
    const int lane = tid & 63;
    const int wv = tid >> 6;
    const int cl = lane & 31;
    const int g  = lane >> 5;
    const int wm = wv & 1;
    const int wn = wv >> 1;

    __shared__ short sA[3 * 68 * 32];   // 13056 B

    const int ow = wm * 32 + cl;
    const int ecol = wn * 32 + cl;
    const short* wbr = w2c + br * 9 * 4096;

    f32x16 acc = {0.f, 0.f, 0.f, 0.f, 0.f, 0.f, 0.f, 0.f,
                  0.f, 0.f, 0.f, 0.f, 0.f, 0.f, 0.f, 0.f};

    // zero border rows once: i in {0,1,66,67}, 4 slots, 3 r = 48 chunks.
    if (tid < 48) {
        int s  = tid & 3;
        int ii = (tid >> 2) & 3;
        int r  = tid >> 4;
        int i  = (ii < 2) ? ii : (64 + ii);
        short8 z = {0, 0, 0, 0, 0, 0, 0, 0};
        *(short8*)((char*)sA + (r * 68 + i) * 64 + s * 16) = z;
    }

    for (int ph = 0; ph < 4; ++ph) {
        // stage: 768 chunks of 16B (r, iw, c8h); 3 iters, r wave-uniform.
        for (int it = 0; it < 3; ++it) {
            int flat = it * 256 + tid;
            int c8h = flat & 1;
            int iw  = (flat >> 1) & 127;
            int r   = flat >> 8;
            int ih  = 2 * oh + (r - 1) * d;
            int iw4 = iw + 4;
            int i   = iw4 >> 1;
            int p   = iw4 & 1;
            char* dst = (char*)sA + (r * 68 + i) * 64
                      + 16 * ((p * 2 + c8h) ^ ((i >> 1) & 3));
            if ((unsigned)ih < 128u) {             // wave-uniform
                const float* src = x + ((size_t)(b * 16384 + ih * 128 + iw)) * 64
                                 + ph * 16 + c8h * 8;
                float4 f0 = *(const float4*)(src);
                float4 f1 = *(const float4*)(src + 4);
                short8 v;
                v[0] = f2bf(f0.x); v[1] = f2bf(f0.y); v[2] = f2bf(f0.z); v[3] = f2bf(f0.w);
                v[4] = f2bf(f1.x); v[5] = f2bf(f1.y); v[6] = f2bf(f1.z); v[7] = f2bf(f1.w);
                *(short8*)dst = v;
            } else {
                short8 z = {0, 0, 0, 0, 0, 0, 0, 0};
                *(short8*)dst = z;
            }
        }
        __syncthreads();

        // compute: 9 taps x 1 MFMA (K = 16 c of this phase), branch-free.
#pragma unroll
        for (int r = 0; r < 3; ++r) {
#pragma unroll
            for (int kwi = 0; kwi < 3; ++kwi) {
                const int iw4 = 2 * ow + (kwi - 1) * d + 4;   // in [1,133]
                const int i   = iw4 >> 1;
                const int p   = iw4 & 1;
                short8 a = *(const short8*)((char*)sA + (r * 68 + i) * 64
                           + 16 * ((p * 2 + g) ^ ((i >> 1) & 3)));
                short8 bf = *(const short8*)(wbr + (r * 3 + kwi) * 4096
                           + ((ph * 2 + g) * 64 + ecol) * 8);
                acc = __builtin_amdgcn_mfma_f32_32x32x16_bf16(a, bf, acc, 0, 0, 0);
            }
        }
        __syncthreads();
    }

    // epilogue: bias + GELU -> LDS tile [64 ow][66] -> coalesced stores.
    {
        const int eG = br * 64 + wn * 32 + cl;
        const float bias = cb[eG];
#pragma unroll
        for (int reg = 0; reg < 16; ++reg) {
            int owl = wm * 32 + (reg & 3) + 8 * (reg >> 2) + 4 * g;
            sA[owl * 66 + wn * 32 + cl] = f2bf(gelu_fast(acc[reg] + bias));
        }
    }
    __syncthreads();
    {
        const int tr = tid >> 2, c16 = tid & 3;
        short8 v0 = *(const short8*)(sA + tr * 66 + c16 * 16);
        short8 v1 = *(const short8*)(sA + tr * 66 + c16 * 16 + 8);
        short* ob = tokens + ((size_t)(b * TOK + oh * 64 + tr)) * 192
                  + br * 64 + c16 * 16;
        *(short8*)(ob) = v0;
        *(short8*)(ob + 8) = v1;
    }
}

// ---------------------------------------------------------------------------
// LN1 + kqv + performer features, all MFMA (r12/r16, unchanged).
// ---------------------------------------------------------------------------
__global__ __launch_bounds__(256) void k_lnkqvp(
        const short* __restrict__ tokens, const float* __restrict__ g,
        const float* __restrict__ be, const short* __restrict__ wbf,
        const float* __restrict__ bias, const short* __restrict__ wpbf,
        short* __restrict__ vT, short* __restrict__ kpT,
        short* __restrict__ qpT) {
    const int b = blockIdx.y;
    const int t0 = blockIdx.x * 64;
    const int tid = threadIdx.x;

    __shared__ short sB[64 * 192];
    __shared__ float red[64 * 8];
    __shared__ float xdk[128];
    __shared__ float xdq[128];

    const int r = tid >> 2, q = tid & 3;
    const short* rowp = tokens + ((size_t)(b * TOK + t0 + r)) * 192 + q * 48;
    float v[48];
    float s1 = 0.f, s2 = 0.f;
#pragma unroll
    for (int i = 0; i < 6; ++i) {
        short8 x8 = *(const short8*)(rowp + i * 8);
#pragma unroll
        for (int j = 0; j < 8; ++j) {
            float f = bf2f(x8[j]);
            v[i * 8 + j] = f;
            s1 += f;
            s2 = fmaf(f, f, s2);
        }
    }
    red[r * 8 + q] = s1;
    red[r * 8 + 4 + q] = s2;
    __syncthreads();
    const float m1 = red[r * 8 + 0] + red[r * 8 + 1] + red[r * 8 + 2] + red[r * 8 + 3];
    const float m2 = red[r * 8 + 4] + red[r * 8 + 5] + red[r * 8 + 6] + red[r * 8 + 7];
    const float mu = m1 * (1.f / 192.f);
    const float var = m2 * (1.f / 192.f) - mu * mu;
    const float rs = rsqrtf(fmaxf(var, 0.f) + 1e-5f);
    const float4* g4 = (const float4*)(g + q * 48);
    const float4* b4 = (const float4*)(be + q * 48);
    char* rowB = (char*)sB + r * 384;
    const int swz = (r & 7) << 4;
#pragma unroll
    for (int i = 0; i < 12; ++i) {
        float4 gg = g4[i], bb = b4[i];
        short4v pk;
        pk.x = f2bf((v[4 * i + 0] - mu) * rs * gg.x + bb.x);
        pk.y = f2bf((v[4 * i + 1] - mu) * rs * gg.y + bb.y);
        pk.z = f2bf((v[4 * i + 2] - mu) * rs * gg.z + bb.z);
        pk.w = f2bf((v[4 * i + 3] - mu) * rs * gg.w + bb.w);
        *(short4v*)(rowB + (((q * 48 + i * 4) * 2) ^ swz)) = pk;
    }
    __syncthreads();

    const int lane = tid & 63;
    const int wv = tid >> 6;
    const int tt = wv & 1;
    const int wo = wv >> 1;
    const int colL = lane & 31;
    const int gq = lane >> 5;

    f32x16 acc0 = {0.f, 0.f, 0.f, 0.f, 0.f, 0.f, 0.f, 0.f,
                   0.f, 0.f, 0.f, 0.f, 0.f, 0.f, 0.f, 0.f};
    f32x16 acc1 = acc0, acc2 = acc0;
    const char* bbase = (const char*)sB + (tt * 32 + colL) * 384;
    const int bswz = ((tt * 32 + colL) & 7) << 4;
    const int ocol = wo * 32 + colL;

    for (int kk = 0; kk < 12; ++kk) {
        short8 bf = *(const short8*)(bbase + (((kk * 16 + gq * 8) * 2) ^ bswz));
        const short* ak = wbf + ((kk * 2 + gq) * 192 + ocol) * 8;
        short8 a0 = *(const short8*)(ak);
        short8 a1 = *(const short8*)(ak + 64 * 8);
        short8 a2 = *(const short8*)(ak + 128 * 8);
        acc0 = __builtin_amdgcn_mfma_f32_32x32x16_bf16(a0, bf, acc0, 0, 0, 0);
        acc1 = __builtin_amdgcn_mfma_f32_32x32x16_bf16(a1, bf, acc1, 0, 0, 0);
        acc2 = __builtin_amdgcn_mfma_f32_32x32x16_bf16(a2, bf, acc2, 0, 0, 0);
    }

    const int tl = tt * 32 + colL;
    const int tglob = t0 + tl;

    float kb[16], qb[16];
    float sk = 0.f, sq = 0.f;
    {
        short* vb = vT + (size_t)b * 64 * TOK + tglob;
#pragma unroll
        for (int reg = 0; reg < 16; ++reg) {
            int orow = (reg & 3) + 8 * (reg >> 2) + 4 * gq;
            int d = wo * 32 + orow;
            kb[reg] = acc0[reg] + bias[d];
            qb[reg] = acc1[reg] + bias[64 + d];
            float vv = acc2[reg] + bias[128 + d];
            vb[(size_t)d * TOK] = f2bf(vv);
            sk = fmaf(kb[reg], kb[reg], sk);
            sq = fmaf(qb[reg], qb[reg], sq);
        }
    }
    sk += __shfl_xor(sk, 32, 64);
    sq += __shfl_xor(sq, 32, 64);
    __syncthreads();

    if (gq == 0) {
        xdk[wo * 64 + tl] = 0.5f * sk;
        xdq[wo * 64 + tl] = 0.5f * sq;
    }
    {
        char* kS = (char*)sB;
        char* qS = (char*)sB + 8192;
        const int tswz = (tl & 7) << 4;
#pragma unroll
        for (int rq = 0; rq < 4; ++rq) {
            int d0 = wo * 32 + 8 * rq + 4 * gq;
            short4v pk, pq;
#pragma unroll
            for (int j = 0; j < 4; ++j) {
                ((short*)&pk)[j] = f2bf(kb[rq * 4 + j]);
                ((short*)&pq)[j] = f2bf(qb[rq * 4 + j]);
            }
            *(short4v*)(kS + tl * 128 + ((d0 * 2) ^ tswz)) = pk;
            *(short4v*)(qS + tl * 128 + ((d0 * 2) ^ tswz)) = pq;
        }
    }
    __syncthreads();

    {
        const int pass = wv >> 1;
        const int tt2 = wv & 1;
        const char* S = (char*)sB + pass * 8192;
        const int t2 = tt2 * 32 + colL;
        const int t2swz = (t2 & 7) << 4;
        f32x16 pacc = {0.f, 0.f, 0.f, 0.f, 0.f, 0.f, 0.f, 0.f,
                       0.f, 0.f, 0.f, 0.f, 0.f, 0.f, 0.f, 0.f};
#pragma unroll
        for (int ks = 0; ks < 4; ++ks) {
            short8 a = *(const short8*)(wpbf + ((ks * 2 + gq) * 32 + colL) * 8);
            short8 bb = *(const short8*)(S + t2 * 128 + (((ks * 16 + gq * 8) * 2) ^ t2swz));
            pacc = __builtin_amdgcn_mfma_f32_32x32x16_bf16(a, bb, pacc, 0, 0, 0);
        }
        const float* xda = pass ? xdq : xdk;
        const float xdv = xda[t2] + xda[64 + t2];
        short* dst = (pass ? qpT : kpT) + (size_t)b * 32 * TOK + t0 + t2;
#pragma unroll
        for (int reg = 0; reg < 16; ++reg) {
            int m = (reg & 3) + 8 * (reg >> 2) + 4 * gq;
            float kpv = __expf(pacc[reg] - xdv) * 0.17677669529663687f;
            dst[(size_t)m * TOK] = f2bf(kpv);
        }
    }
}

// ---------------------------------------------------------------------------
// kptv chunk partials (r12 version: coalesced scalar loads, conflict-free
// LDS writes).
// ---------------------------------------------------------------------------
__global__ __launch_bounds__(256) void k_kptv(
        const short* __restrict__ vT, const short* __restrict__ kpT,
        float* __restrict__ kvp, float* __restrict__ skpp) {
    const int b = blockIdx.y, ch = blockIdx.x, tid = threadIdx.x;
    const int t = ch * 256 + tid;
    __shared__ float sv[256 * 65 + 256 * 36];
    float* skp = sv + 256 * 65;
    for (int dd = 0; dd < 64; ++dd)
        sv[tid * 65 + dd] = bf2f(vT[((size_t)(b * 64 + dd)) * TOK + t]);
    for (int m = 0; m < 32; ++m)
        skp[tid * 36 + m] = bf2f(kpT[((size_t)(b * 32 + m)) * TOK + t]);
    __syncthreads();

    const int dd = tid & 63;
    const int mg = __builtin_amdgcn_readfirstlane(tid >> 6);
    float acc[8];
#pragma unroll
    for (int j = 0; j < 8; ++j) acc[j] = 0.f;
    for (int tt = 0; tt < 256; ++tt) {
        float vv = sv[tt * 65 + dd];
        const float4* kq = (const float4*)(skp + tt * 36 + mg * 8);
        float4 a0 = kq[0], a1 = kq[1];
        acc[0] = fmaf(vv, a0.x, acc[0]);
        acc[1] = fmaf(vv, a0.y, acc[1]);
        acc[2] = fmaf(vv, a0.z, acc[2]);
        acc[3] = fmaf(vv, a0.w, acc[3]);
        acc[4] = fmaf(vv, a1.x, acc[4]);
        acc[5] = fmaf(vv, a1.y, acc[5]);
        acc[6] = fmaf(vv, a1.z, acc[6]);
        acc[7] = fmaf(vv, a1.w, acc[7]);
    }
    float* dst = kvp + (((size_t)(b * 16 + ch) * 64 + dd) * 32) + mg * 8;
#pragma unroll
    for (int j = 0; j < 8; ++j) dst[j] = acc[j];

    if (tid < 32) {
        float s = 0.f;
        for (int tt = 0; tt < 256; ++tt) s += skp[tt * 36 + tid];
        skpp[(b * 16 + ch) * 32 + tid] = s;
    }
}

// Reduce partials -> kvbf MFMA-native, sum_kp fp32 (unchanged).
__global__ __launch_bounds__(256) void k_reduce2(
        const float* __restrict__ kvp, const float* __restrict__ skpp,
        short* __restrict__ kvbf, float* __restrict__ sum_kp) {
    int idx = blockIdx.x * 256 + threadIdx.x;
    if (idx < 65536) {
        int b = idx >> 11, rem = idx & 2047, dd = rem >> 5, m = rem & 31;
        float s = 0.f;
        for (int ch = 0; ch < 16; ++ch) s += kvp[((b * 16 + ch) * 64 + dd) * 32 + m];
        int dst = (((b * 2 + (m >> 4)) * 2 + ((m >> 3) & 1)) * 64 + dd) * 8 + (m & 7);
        kvbf[dst] = f2bf(s);
    } else if (idx < 65536 + 1024) {
        int i = idx - 65536;
        int b = i >> 5, m = i & 31;
        float s = 0.f;
        for (int ch = 0; ch < 16; ++ch) s += skpp[(b * 16 + ch) * 32 + m];
        sum_kp[i] = s;
    }
}

// ---------------------------------------------------------------------------
// Fused tail (r12/r16, unchanged).
// ---------------------------------------------------------------------------
__global__ __launch_bounds__(256) void k_fuse(
        const short* __restrict__ vT, const short* __restrict__ qpT,
        const short* __restrict__ kvbf, const float* __restrict__ sum_kp,
        const short* __restrict__ pTbf, const float* __restrict__ proj_b,
        const float* __restrict__ g2, const float* __restrict__ b2ln,
        const short* __restrict__ w1bf, const float* __restrict__ b1,
        const short* __restrict__ w2bf, const float* __restrict__ b2,
        float* __restrict__ out) {
    const int b = blockIdx.y;
    const int t0 = blockIdx.x * 64;
    const int tid = threadIdx.x;
    const int lane = tid & 63;
    const int cl = lane & 31;
    const int g  = lane >> 5;
    const int wv = tid >> 6;
    const int wr = wv & 1;
    const int wc = wv >> 1;

    __shared__ __align__(16) char pool[29952];
    short* qpS  = (short*)(pool + 0);
    short* ytS  = (short*)(pool + 5120);
    short* xnS  = (short*)(pool + 14336);
    short* hgS  = (short*)(pool + 0);
    float* outS = (float*)(pool + 9216);
    float* red  = (float*)(pool + 26624);
    float* stat = (float*)(pool + 27648);
    float* coefS= (float*)(pool + 28672);

    if (tid < 64) {
        coefS[tid]       = proj_b[tid];
        coefS[64 + tid]  = g2[tid];
        coefS[128 + tid] = b2ln[tid];
        coefS[192 + tid] = b1[tid];
        coefS[256 + tid] = b2[tid];
    }
    {
        const int t = tid & 63, q = tid >> 6;
        const float* sk = sum_kp + b * 32;
        float dsum = 0.f;
        short8 pk;
#pragma unroll
        for (int i = 0; i < 8; ++i) {
            int m = q * 8 + i;
            short s = qpT[((size_t)(b * 32 + m)) * TOK + t0 + t];
            dsum = fmaf(bf2f(s), sk[m], dsum);
            pk[i] = s;
        }
        *(short8*)(qpS + t * 40 + q * 8) = pk;
        red[t * 4 + q] = dsum;
    }
    __syncthreads();

    const int tl = wc * 32 + cl;
    const int tg = t0 + tl;
    const int rcol = wr * 32 + cl;

    f32x16 acc = {0.f, 0.f, 0.f, 0.f, 0.f, 0.f, 0.f, 0.f,
                  0.f, 0.f, 0.f, 0.f, 0.f, 0.f, 0.f, 0.f};
    {
        const short* Ab = kvbf + (size_t)b * 2048;
        short8 a0 = *(const short8*)(Ab + (g * 64 + rcol) * 8);
        short8 a1 = *(const short8*)(Ab + ((2 + g) * 64 + rcol) * 8);
        short8 b0 = *(const short8*)(qpS + tl * 40 + g * 8);
        short8 b1v = *(const short8*)(qpS + tl * 40 + 16 + g * 8);
        acc = __builtin_amdgcn_mfma_f32_32x32x16_bf16(a0, b0, acc, 0, 0, 0);
        acc = __builtin_amdgcn_mfma_f32_32x32x16_bf16(a1, b1v, acc, 0, 0, 0);
    }
    {
        float Dv = red[tl * 4 + 0] + red[tl * 4 + 1] + red[tl * 4 + 2] + red[tl * 4 + 3];
        float rD = 1.f / (Dv + 1e-8f);
#pragma unroll
        for (int rq = 0; rq < 4; ++rq) {
            int d0 = wr * 32 + 8 * rq + 4 * g;
            short4v p;
            p.x = f2bf(acc[rq * 4 + 0] * rD);
            p.y = f2bf(acc[rq * 4 + 1] * rD);
            p.z = f2bf(acc[rq * 4 + 2] * rD);
            p.w = f2bf(acc[rq * 4 + 3] * rD);
            *(short4v*)(ytS + tl * 72 + d0) = p;
        }
    }
    __syncthreads();

    f32x16 acc2 = {0.f, 0.f, 0.f, 0.f, 0.f, 0.f, 0.f, 0.f,
                   0.f, 0.f, 0.f, 0.f, 0.f, 0.f, 0.f, 0.f};
    {
#pragma unroll
        for (int ks = 0; ks < 4; ++ks) {
            short8 a = *(const short8*)(pTbf + ((ks * 2 + g) * 64 + rcol) * 8);
            short8 bb = *(const short8*)(ytS + tl * 72 + ks * 16 + g * 8);
            acc2 = __builtin_amdgcn_mfma_f32_32x32x16_bf16(a, bb, acc2, 0, 0, 0);
        }
    }
    float skv[16];
    {
        const short* vb = vT + (size_t)b * 64 * TOK + tg;
#pragma unroll
        for (int reg = 0; reg < 16; ++reg) {
            int o = wr * 32 + (reg & 3) + 8 * (reg >> 2) + 4 * g;
            skv[reg] = acc2[reg] + bf2f(vb[(size_t)o * TOK]) + coefS[o];
        }
    }

    {
        float s1 = 0.f, s2 = 0.f;
#pragma unroll
        for (int reg = 0; reg < 16; ++reg) {
            s1 += skv[reg];
            s2 = fmaf(skv[reg], skv[reg], s2);
        }
        s1 += __shfl_xor(s1, 32, 64);
        s2 += __shfl_xor(s2, 32, 64);
        if (g == 0) {
            stat[(wr * 64 + tl) * 2 + 0] = s1;
            stat[(wr * 64 + tl) * 2 + 1] = s2;
        }
        __syncthreads();
        float S1 = s1 + stat[((wr ^ 1) * 64 + tl) * 2 + 0];
        float S2 = s2 + stat[((wr ^ 1) * 64 + tl) * 2 + 1];
        float mu = S1 * (1.f / 64.f);
        float var = S2 * (1.f / 64.f) - mu * mu;
        float rs = rsqrtf(fmaxf(var, 0.f) + 1e-5f);
#pragma unroll
        for (int rq = 0; rq < 4; ++rq) {
            int o0 = wr * 32 + 8 * rq + 4 * g;
            short4v p;
#pragma unroll
            for (int j = 0; j < 4; ++j) {
                int o = o0 + j;
                float xn = (skv[rq * 4 + j] - mu) * rs * coefS[64 + o] + coefS[128 + o];
                ((short*)&p)[j] = f2bf(xn);
            }
            *(short4v*)(xnS + tl * 72 + o0) = p;
        }
    }
    __syncthreads();

    f32x16 acc3 = {0.f, 0.f, 0.f, 0.f, 0.f, 0.f, 0.f, 0.f,
                   0.f, 0.f, 0.f, 0.f, 0.f, 0.f, 0.f, 0.f};
    {
#pragma unroll
        for (int ks = 0; ks < 4; ++ks) {
            short8 a = *(const short8*)(w1bf + ((ks * 2 + g) * 64 + rcol) * 8);
            short8 bb = *(const short8*)(xnS + tl * 72 + ks * 16 + g * 8);
            acc3 = __builtin_amdgcn_mfma_f32_32x32x16_bf16(a, bb, acc3, 0, 0, 0);
        }
    }
    __syncthreads();
    {
#pragma unroll
        for (int rq = 0; rq < 4; ++rq) {
            int i0 = wr * 32 + 8 * rq + 4 * g;
            short4v p;
#pragma unroll
            for (int j = 0; j < 4; ++j) {
                int i = i0 + j;
                float hgv = gelu_fast(acc3[rq * 4 + j] + coefS[192 + i]);
                ((short*)&p)[j] = f2bf(hgv);
            }
            *(short4v*)(hgS + tl * 72 + i0) = p;
        }
    }
    __syncthreads();

    f32x16 acc4 = {0.f, 0.f, 0.f, 0.f, 0.f, 0.f, 0.f, 0.f,
                   0.f, 0.f, 0.f, 0.f, 0.f, 0.f, 0.f, 0.f};
    {
#pragma unroll
        for (int ks = 0; ks < 4; ++ks) {
            short8 a = *(const short8*)(w2bf + ((ks * 2 + g) * 64 + rcol) * 8);
            short8 bb = *(const short8*)(hgS + tl * 72 + ks * 16 + g * 8);
            acc4 = __builtin_amdgcn_mfma_f32_32x32x16_bf16(a, bb, acc4, 0, 0, 0);
        }
    }
    {
#pragma unroll
        for (int rq = 0; rq < 4; ++rq) {
            int o0 = wr * 32 + 8 * rq + 4 * g;
            float4 f;
#pragma unroll
            for (int j = 0; j < 4; ++j) {
                int o = o0 + j;
                ((float*)&f)[j] = skv[rq * 4 + j] + acc4[rq * 4 + j] + coefS[256 + o];
            }
            *(float4*)(outS + tl * 68 + o0) = f;
        }
    }
    __syncthreads();

    {
        const int tt = tid >> 2, qq = tid & 3;
        float* ob = out + ((size_t)(b * TOK) + t0 + tt) * 64;
#pragma unroll
        for (int it = 0; it < 4; ++it) {
            *(float4*)(ob + it * 16 + qq * 4) =
                *(float4*)(outS + tt * 68 + it * 16 + qq * 4);
        }
    }
}

// ---------------------------------------------------------------------------
extern "C" void kernel_launch(void* const* d_in, const int* in_sizes, int n_in,
                              void* d_out, int out_size, void* d_ws, size_t ws_size,
                              hipStream_t stream) {
    const float* x      = (const float*)d_in[0];
    const float* conv_w = (const float*)d_in[1];
    const float* conv_b = (const float*)d_in[2];
    const float* ln1_g  = (const float*)d_in[3];
    const float* ln1_b  = (const float*)d_in[4];
    const float* kqv_w  = (const float*)d_in[5];
    const float* kqv_b  = (const float*)d_in[6];
    const float* proj_w = (const float*)d_in[7];
    const float* proj_b = (const float*)d_in[8];
    const float* w_perf = (const float*)d_in[9];
    const float* ln2_g  = (const float*)d_in[10];
    const float* ln2_b  = (const float*)d_in[11];
    const float* mlp_w1 = (const float*)d_in[12];
    const float* mlp_b1 = (const float*)d_in[13];
    const float* mlp_w2 = (const float*)d_in[14];
    const float* mlp_b2 = (const float*)d_in[15];

    float* ws = (float*)d_ws;
    short* w2c    = (short*)ws;                 // 110592 sh
    short* kwbf   = (short*)(ws + 55296);       // 36864 sh
    short* pTbf   = (short*)(ws + 73728);       // 4096 sh
    short* w1bf   = (short*)(ws + 75776);       // 4096 sh
    short* w2bf   = (short*)(ws + 77824);       // 4096 sh
    short* wpbf   = (short*)(ws + 79872);       // 2048 sh
    float* sum_kp = ws + 80896;                 // 1024 f
    short* kvbf   = (short*)(ws + 81920);       // 65536 sh -> ends ws+114688
    // tokens bf16 (dead after lnkqvp)
    short* tokens = (short*)(ws + 114688);      // 25165824 sh
    // region B: outputs of lnkqvp (must not alias tokens)
    float* wsB    = ws + 114688 + 12582912;
    short* vT     = (short*)wsB;                // 8388608 sh
    short* qpT    = (short*)(wsB + 4194304);    // 4194304 sh
    short* kpT    = (short*)(wsB + 6291456);    // 4194304 sh
    float* skpp   = wsB + 8388608;              // 16384 f
    float* kvp    = wsB + 8404992;              // 1048576 f
    float* outp   = (float*)d_out;

    k_prep   <<<632, 256, 0, stream>>>(conv_w, kqv_w, proj_w, mlp_w1, mlp_w2,
                                       w_perf, w2c, kwbf, pTbf, w1bf, w2bf, wpbf);
    k_conv9  <<<6144, 256, 0, stream>>>(x, w2c, conv_b, tokens);
    k_lnkqvp <<<dim3(64, 32), 256, 0, stream>>>(tokens, ln1_g, ln1_b, kwbf,
                                                kqv_b, wpbf, vT, kpT, qpT);
    k_kptv   <<<dim3(16, 32), 256, 0, stream>>>(vT, kpT, kvp, skpp);
    k_reduce2<<<260, 256, 0, stream>>>(kvp, skpp, kvbf, sum_kp);
    k_fuse   <<<dim3(64, 32), 256, 0, stream>>>(vT, qpT, kvbf, sum_kp,
                                                pTbf, proj_b, ln2_g, ln2_b,
                                                w1bf, mlp_b1, w2bf, mlp_b2, outp);
}

// Round 18
// 132.382 us; speedup vs baseline: 1.2333x; 1.2333x over previous
//
#include <hip/hip_runtime.h>
#include <hip/hip_bf16.h>

// ---------------------------------------------------------------------------
// BlockRC2: PRM (3 dilated stride-2 convs + GELU) -> LN1 -> kqv ->
// performer attention -> proj+skip -> LN2 -> MLP -> skip.
// Round 18: conv reverted to measured-best conv6 (r17 falsified the
// occupancy theory: 41->62% occ, no speedup). New: k_kptv -> MFMA
// (was scalar-FMA on a matmul shape, ~2048 VALU FMA + ~770 ds_read/thread).
// Per (b,chunk): stage V[64][256]+KP[32][256] bf16 to LDS (row-XOR swizzle),
// 4 waves = (d-tile x K-half) 32x32 MFMA partials, psum K-reduce, fp32
// kvp partials in the layout reduce2 already consumes.
// ---------------------------------------------------------------------------

#define TOK 4096
#define NB  32

typedef __attribute__((ext_vector_type(8)))  short short8;
typedef __attribute__((ext_vector_type(4)))  short short4v;
typedef __attribute__((ext_vector_type(16))) float f32x16;

// gelu(x) = x * sigmoid(x*(1.5957691216 + 0.0713548162 x^2)), max err ~3e-4.
__device__ __forceinline__ float gelu_fast(float v) {
    float u = v * fmaf(0.0713548162f, v * v, 1.5957691216f);
    float e = __expf(-u);
    return v * __builtin_amdgcn_rcpf(1.f + e);
}

__device__ __forceinline__ short f2bf(float f) {
    __hip_bfloat16 h = __float2bfloat16(f);   // RNE; HW cvt on gfx950
    return *reinterpret_cast<short*>(&h);
}

__device__ __forceinline__ float bf2f(short s) {
    union { unsigned u; float f; } x;
    x.u = ((unsigned)(unsigned short)s) << 16;
    return x.f;
}

// ---------------------------------------------------------------------------
// Prep. MFMA-native layouts: frag element for lane (cl,g), reg j is
// W[col=cl][k = ks*16 + g*8 + j]  ->  stored at ((ks*2+g)*NCOL + col)*8 + j.
// ---------------------------------------------------------------------------
__global__ __launch_bounds__(256) void k_prep(
        const float* __restrict__ cw, const float* __restrict__ kw,
        const float* __restrict__ pw, const float* __restrict__ w1,
        const float* __restrict__ w2m, const float* __restrict__ wperf,
        short* __restrict__ w2c, short* __restrict__ kwbf,
        short* __restrict__ pTbf, short* __restrict__ w1bf,
        short* __restrict__ w2bf, short* __restrict__ wpbf) {
    int idx = blockIdx.x * 256 + threadIdx.x;
    if (idx < 110592) {
        int c = idx & 63;
        int t = idx >> 6;
        int e = t & 63;
        int tap = t >> 6;
        int kwi = tap % 3, t2 = tap / 3;
        int r = t2 % 3, brr = t2 / 3;
        float v = cw[(((brr * 64 + e) * 64 + c) * 3 + r) * 3 + kwi];
        int dst = ((((brr * 9 + r * 3 + kwi) * 4 + (c >> 4)) * 2 + ((c >> 3) & 1)) * 64 + e) * 8 + (c & 7);
        w2c[dst] = f2bf(v);
    } else if (idx < 147456) {
        int i2 = idx - 110592;
        int o = i2 / 192, i = i2 % 192;
        int dst = (((i >> 4) * 2 + ((i >> 3) & 1)) * 192 + o) * 8 + (i & 7);
        kwbf[dst] = f2bf(kw[i * 192 + o]);
    } else if (idx < 151552) {
        int i2 = idx - 147456;
        int o = i2 >> 6, d = i2 & 63;
        int dst = (((d >> 4) * 2 + ((d >> 3) & 1)) * 64 + o) * 8 + (d & 7);
        pTbf[dst] = f2bf(pw[d * 64 + o]);
    } else if (idx < 155648) {
        int i2 = idx - 151552;
        int i = i2 >> 6, jd = i2 & 63;
        int dst = (((jd >> 4) * 2 + ((jd >> 3) & 1)) * 64 + i) * 8 + (jd & 7);
        w1bf[dst] = f2bf(w1[jd * 64 + i]);
    } else if (idx < 159744) {
        int i2 = idx - 155648;
        int o = i2 >> 6, i = i2 & 63;
        int dst = (((i >> 4) * 2 + ((i >> 3) & 1)) * 64 + o) * 8 + (i & 7);
        w2bf[dst] = f2bf(w2m[i * 64 + o]);
    } else if (idx < 161792) {
        int i2 = idx - 159744;
        int m = i2 >> 6, d = i2 & 63;       // w_perf [m=32][d=64]
        int dst = (((d >> 4) * 2 + ((d >> 3) & 1)) * 32 + m) * 8 + (d & 7);
        wpbf[dst] = f2bf(wperf[m * 64 + d]);
    }
}

// ---------------------------------------------------------------------------
// Conv via MFMA, c-split 2-phase (measured-best conv6, ~107us).
// ---------------------------------------------------------------------------
__global__ __launch_bounds__(256) void k_conv6(
        const float* __restrict__ x, const short* __restrict__ w2c,
        const float* __restrict__ cb, short* __restrict__ tokens) {
    const int wg  = blockIdx.x;
    const int swz_id = (wg & 7) * 768 + (wg >> 3);   // 6144 = 8*768, bijective
    const int b   = swz_id / 192;
    const int rem = swz_id - b * 192;
    const int oh  = rem / 3;
    const int br  = rem - oh * 3;
    const int d   = br + 1;
    const int tid = threadIdx.x;
    const int lane = tid & 63;
    const int wv = tid >> 6;
    const int cl = lane & 31;
    const int g  = lane >> 5;
    const int wm = wv & 1;
    const int wn = wv >> 1;

    __shared__ short sA[3 * 68 * 2 * 32];   // 26112 B

    const int ow = wm * 32 + cl;
    const int ecol = wn * 32 + cl;
    const short* wbr = w2c + br * 9 * 4096;

    f32x16 acc = {0.f, 0.f, 0.f, 0.f, 0.f, 0.f, 0.f, 0.f,
                  0.f, 0.f, 0.f, 0.f, 0.f, 0.f, 0.f, 0.f};

    for (int h = 0; h < 2; ++h) {
        if (h == 0 && tid < 96) {
            int s16 = tid & 7;
            int ii  = (tid >> 3) & 3;
            int r   = tid >> 5;
            int i   = (ii < 2) ? ii : (64 + ii);
            short8 z = {0, 0, 0, 0, 0, 0, 0, 0};
            *(short8*)((char*)sA + (r * 68 + i) * 128 + s16 * 16) = z;
        }
        for (int it = 0; it < 6; ++it) {
            int flat = it * 256 + tid;
            int c8l = flat & 3;
            int iw  = (flat >> 2) & 127;
            int r   = flat >> 9;
            int ih  = 2 * oh + (r - 1) * d;
            int iw4 = iw + 4;
            int i   = iw4 >> 1;
            int p   = iw4 & 1;
            char* dst = (char*)sA + (r * 68 + i) * 128
                      + ((((p * 4 + c8l) * 16)) ^ ((i & 7) << 4));
            if ((unsigned)ih < 128u) {
                const float* src = x + ((size_t)(b * 16384 + ih * 128 + iw)) * 64
                                 + h * 32 + c8l * 8;
                float4 f0 = *(const float4*)(src);
                float4 f1 = *(const float4*)(src + 4);
                short8 v;
                v[0] = f2bf(f0.x); v[1] = f2bf(f0.y); v[2] = f2bf(f0.z); v[3] = f2bf(f0.w);
                v[4] = f2bf(f1.x); v[5] = f2bf(f1.y); v[6] = f2bf(f1.z); v[7] = f2bf(f1.w);
                *(short8*)dst = v;
            } else {
                short8 z = {0, 0, 0, 0, 0, 0, 0, 0};
                *(short8*)dst = z;
            }
        }
        __syncthreads();

#pragma unroll
        for (int r = 0; r < 3; ++r) {
#pragma unroll
            for (int kwi = 0; kwi < 3; ++kwi) {
                const int iw4 = 2 * ow + (kwi - 1) * d + 4;   // in [1,133]
                const int i   = iw4 >> 1;
                const int p   = iw4 & 1;
                const char* arow = (const char*)sA + (r * 68 + i) * 128;
                const int swzk = (i & 7) << 4;
                const short* wt = wbr + (r * 3 + kwi) * 4096;
#pragma unroll
                for (int kk = 0; kk < 2; ++kk) {
                    const int ks = h * 2 + kk;
                    short8 a = *(const short8*)(arow + ((((p * 4 + kk * 2 + g) * 16)) ^ swzk));
                    short8 bf = *(const short8*)(wt + ((ks * 2 + g) * 64 + ecol) * 8);
                    acc = __builtin_amdgcn_mfma_f32_32x32x16_bf16(a, bf, acc, 0, 0, 0);
                }
            }
        }
        __syncthreads();
    }

    // epilogue via LDS tile (r16, measured equal to scalar stores).
    {
        const int eG = br * 64 + wn * 32 + cl;
        const float bias = cb[eG];
#pragma unroll
        for (int reg = 0; reg < 16; ++reg) {
            int owl = wm * 32 + (reg & 3) + 8 * (reg >> 2) + 4 * g;
            sA[owl * 66 + wn * 32 + cl] = f2bf(gelu_fast(acc[reg] + bias));
        }
    }
    __syncthreads();
    {
        const int tr = tid >> 2, c16 = tid & 3;
        short8 v0 = *(const short8*)(sA + tr * 66 + c16 * 16);
        short8 v1 = *(const short8*)(sA + tr * 66 + c16 * 16 + 8);
        short* ob = tokens + ((size_t)(b * TOK + oh * 64 + tr)) * 192
                  + br * 64 + c16 * 16;
        *(short8*)(ob) = v0;
        *(short8*)(ob + 8) = v1;
    }
}

// ---------------------------------------------------------------------------
// LN1 + kqv + performer features, all MFMA (r12/r16, unchanged).
// ---------------------------------------------------------------------------
__global__ __launch_bounds__(256) void k_lnkqvp(
        const short* __restrict__ tokens, const float* __restrict__ g,
        const float* __restrict__ be, const short* __restrict__ wbf,
        const float* __restrict__ bias, const short* __restrict__ wpbf,
        short* __restrict__ vT, short* __restrict__ kpT,
        short* __restrict__ qpT) {
    const int b = blockIdx.y;
    const int t0 = blockIdx.x * 64;
    const int tid = threadIdx.x;

    __shared__ short sB[64 * 192];
    __shared__ float red[64 * 8];
    __shared__ float xdk[128];
    __shared__ float xdq[128];

    const int r = tid >> 2, q = tid & 3;
    const short* rowp = tokens + ((size_t)(b * TOK + t0 + r)) * 192 + q * 48;
    float v[48];
    float s1 = 0.f, s2 = 0.f;
#pragma unroll
    for (int i = 0; i < 6; ++i) {
        short8 x8 = *(const short8*)(rowp + i * 8);
#pragma unroll
        for (int j = 0; j < 8; ++j) {
            float f = bf2f(x8[j]);
            v[i * 8 + j] = f;
            s1 += f;
            s2 = fmaf(f, f, s2);
        }
    }
    red[r * 8 + q] = s1;
    red[r * 8 + 4 + q] = s2;
    __syncthreads();
    const float m1 = red[r * 8 + 0] + red[r * 8 + 1] + red[r * 8 + 2] + red[r * 8 + 3];
    const float m2 = red[r * 8 + 4] + red[r * 8 + 5] + red[r * 8 + 6] + red[r * 8 + 7];
    const float mu = m1 * (1.f / 192.f);
    const float var = m2 * (1.f / 192.f) - mu * mu;
    const float rs = rsqrtf(fmaxf(var, 0.f) + 1e-5f);
    const float4* g4 = (const float4*)(g + q * 48);
    const float4* b4 = (const float4*)(be + q * 48);
    char* rowB = (char*)sB + r * 384;
    const int swz = (r & 7) << 4;
#pragma unroll
    for (int i = 0; i < 12; ++i) {
        float4 gg = g4[i], bb = b4[i];
        short4v pk;
        pk.x = f2bf((v[4 * i + 0] - mu) * rs * gg.x + bb.x);
        pk.y = f2bf((v[4 * i + 1] - mu) * rs * gg.y + bb.y);
        pk.z = f2bf((v[4 * i + 2] - mu) * rs * gg.z + bb.z);
        pk.w = f2bf((v[4 * i + 3] - mu) * rs * gg.w + bb.w);
        *(short4v*)(rowB + (((q * 48 + i * 4) * 2) ^ swz)) = pk;
    }
    __syncthreads();

    const int lane = tid & 63;
    const int wv = tid >> 6;
    const int tt = wv & 1;
    const int wo = wv >> 1;
    const int colL = lane & 31;
    const int gq = lane >> 5;

    f32x16 acc0 = {0.f, 0.f, 0.f, 0.f, 0.f, 0.f, 0.f, 0.f,
                   0.f, 0.f, 0.f, 0.f, 0.f, 0.f, 0.f, 0.f};
    f32x16 acc1 = acc0, acc2 = acc0;
    const char* bbase = (const char*)sB + (tt * 32 + colL) * 384;
    const int bswz = ((tt * 32 + colL) & 7) << 4;
    const int ocol = wo * 32 + colL;

    for (int kk = 0; kk < 12; ++kk) {
        short8 bf = *(const short8*)(bbase + (((kk * 16 + gq * 8) * 2) ^ bswz));
        const short* ak = wbf + ((kk * 2 + gq) * 192 + ocol) * 8;
        short8 a0 = *(const short8*)(ak);
        short8 a1 = *(const short8*)(ak + 64 * 8);
        short8 a2 = *(const short8*)(ak + 128 * 8);
        acc0 = __builtin_amdgcn_mfma_f32_32x32x16_bf16(a0, bf, acc0, 0, 0, 0);
        acc1 = __builtin_amdgcn_mfma_f32_32x32x16_bf16(a1, bf, acc1, 0, 0, 0);
        acc2 = __builtin_amdgcn_mfma_f32_32x32x16_bf16(a2, bf, acc2, 0, 0, 0);
    }

    const int tl = tt * 32 + colL;
    const int tglob = t0 + tl;

    float kb[16], qb[16];
    float sk = 0.f, sq = 0.f;
    {
        short* vb = vT + (size_t)b * 64 * TOK + tglob;
#pragma unroll
        for (int reg = 0; reg < 16; ++reg) {
            int orow = (reg & 3) + 8 * (reg >> 2) + 4 * gq;
            int d = wo * 32 + orow;
            kb[reg] = acc0[reg] + bias[d];
            qb[reg] = acc1[reg] + bias[64 + d];
            float vv = acc2[reg] + bias[128 + d];
            vb[(size_t)d * TOK] = f2bf(vv);
            sk = fmaf(kb[reg], kb[reg], sk);
            sq = fmaf(qb[reg], qb[reg], sq);
        }
    }
    sk += __shfl_xor(sk, 32, 64);
    sq += __shfl_xor(sq, 32, 64);
    __syncthreads();

    if (gq == 0) {
        xdk[wo * 64 + tl] = 0.5f * sk;
        xdq[wo * 64 + tl] = 0.5f * sq;
    }
    {
        char* kS = (char*)sB;
        char* qS = (char*)sB + 8192;
        const int tswz = (tl & 7) << 4;
#pragma unroll
        for (int rq = 0; rq < 4; ++rq) {
            int d0 = wo * 32 + 8 * rq + 4 * gq;
            short4v pk, pq;
#pragma unroll
            for (int j = 0; j < 4; ++j) {
                ((short*)&pk)[j] = f2bf(kb[rq * 4 + j]);
                ((short*)&pq)[j] = f2bf(qb[rq * 4 + j]);
            }
            *(short4v*)(kS + tl * 128 + ((d0 * 2) ^ tswz)) = pk;
            *(short4v*)(qS + tl * 128 + ((d0 * 2) ^ tswz)) = pq;
        }
    }
    __syncthreads();

    {
        const int pass = wv >> 1;
        const int tt2 = wv & 1;
        const char* S = (char*)sB + pass * 8192;
        const int t2 = tt2 * 32 + colL;
        const int t2swz = (t2 & 7) << 4;
        f32x16 pacc = {0.f, 0.f, 0.f, 0.f, 0.f, 0.f, 0.f, 0.f,
                       0.f, 0.f, 0.f, 0.f, 0.f, 0.f, 0.f, 0.f};
#pragma unroll
        for (int ks = 0; ks < 4; ++ks) {
            short8 a = *(const short8*)(wpbf + ((ks * 2 + gq) * 32 + colL) * 8);
            short8 bb = *(const short8*)(S + t2 * 128 + (((ks * 16 + gq * 8) * 2) ^ t2swz));
            pacc = __builtin_amdgcn_mfma_f32_32x32x16_bf16(a, bb, pacc, 0, 0, 0);
        }
        const float* xda = pass ? xdq : xdk;
        const float xdv = xda[t2] + xda[64 + t2];
        short* dst = (pass ? qpT : kpT) + (size_t)b * 32 * TOK + t0 + t2;
#pragma unroll
        for (int reg = 0; reg < 16; ++reg) {
            int m = (reg & 3) + 8 * (reg >> 2) + 4 * gq;
            float kpv = __expf(pacc[reg] - xdv) * 0.17677669529663687f;
            dst[(size_t)m * TOK] = f2bf(kpv);
        }
    }
}

// ---------------------------------------------------------------------------
// kptv via MFMA. Block = (ch, b): kvp_part[d][m] = sum_t V[d][t]*KP[m][t]
// over t in [ch*256, ch*256+256). Stage V[64][256] + KP[32][256] bf16 into
// LDS (512B rows, XOR swizzle ^((row&7)<<4)); 4 waves = (dtile = wv&1,
// khalf = wv>>1), 8 MFMA each; psum K-reduce; fp32 partials -> kvp in the
// layout k_reduce2 already consumes. skpp from the staged KP tile.
// ---------------------------------------------------------------------------
__global__ __launch_bounds__(256) void k_kptv(
        const short* __restrict__ vT, const short* __restrict__ kpT,
        float* __restrict__ kvp, float* __restrict__ skpp) {
    const int b = blockIdx.y, ch = blockIdx.x, tid = threadIdx.x;
    const int lane = tid & 63;
    const int wv = tid >> 6;
    const int cl = lane & 31;
    const int g  = lane >> 5;
    const int dtile = wv & 1;
    const int khalf = wv >> 1;

    __shared__ short sV[64 * 256];      // 32768 B
    __shared__ short sKP[32 * 256];     // 16384 B
    __shared__ float psum[2 * 32 * 32]; // 8192 B

    // stage V: 2048 x 16B chunks, 8/thread; lanes contiguous in t (coalesced).
    for (int it = 0; it < 8; ++it) {
        int flat = it * 256 + tid;
        int t8 = flat & 31;
        int dd = flat >> 5;
        short8 v = *(const short8*)(vT + ((size_t)(b * 64 + dd)) * TOK
                                    + ch * 256 + t8 * 8);
        *(short8*)((char*)sV + dd * 512 + ((t8 * 16) ^ ((dd & 7) << 4))) = v;
    }
    // stage KP: 1024 x 16B chunks, 4/thread.
    for (int it = 0; it < 4; ++it) {
        int flat = it * 256 + tid;
        int t8 = flat & 31;
        int m = flat >> 5;
        short8 v = *(const short8*)(kpT + ((size_t)(b * 32 + m)) * TOK
                                    + ch * 256 + t8 * 8);
        *(short8*)((char*)sKP + m * 512 + ((t8 * 16) ^ ((m & 7) << 4))) = v;
    }
    __syncthreads();

    // MFMA: A = V (col = d), B = KP (col = m), K = 128 (this wave's half).
    f32x16 acc = {0.f, 0.f, 0.f, 0.f, 0.f, 0.f, 0.f, 0.f,
                  0.f, 0.f, 0.f, 0.f, 0.f, 0.f, 0.f, 0.f};
    const int dcol = dtile * 32 + cl;
    const int dswz = (dcol & 7) << 4;
    const int mswz = (cl & 7) << 4;
#pragma unroll
    for (int ks = 0; ks < 8; ++ks) {
        const int toff = khalf * 256 + ks * 32 + g * 16;   // byte offset (t*2)
        short8 a  = *(const short8*)((char*)sV + dcol * 512 + (toff ^ dswz));
        short8 bb = *(const short8*)((char*)sKP + cl * 512 + (toff ^ mswz));
        acc = __builtin_amdgcn_mfma_f32_32x32x16_bf16(a, bb, acc, 0, 0, 0);
    }

    if (khalf == 1) {
        float* ps = psum + dtile * 1024;
#pragma unroll
        for (int reg = 0; reg < 16; ++reg) {
            int row = (reg & 3) + 8 * (reg >> 2) + 4 * g;
            ps[row * 32 + cl] = acc[reg];
        }
    }
    __syncthreads();

    if (khalf == 0) {
        const float* ps = psum + dtile * 1024;
        float* dst = kvp + ((size_t)(b * 16 + ch) * 64) * 32;
#pragma unroll
        for (int reg = 0; reg < 16; ++reg) {
            int row = (reg & 3) + 8 * (reg >> 2) + 4 * g;
            int dd = dtile * 32 + row;
            dst[dd * 32 + cl] = acc[reg] + ps[row * 32 + cl];
        }
    } else if (dtile == 0 && lane < 32) {
        // wave 2, lanes 0..31: skpp[m] = sum_t KP[m][t] from the staged tile.
        const char* rowp = (const char*)sKP + cl * 512;
        const int sw = (cl & 7) << 4;
        float s = 0.f;
        for (int t8 = 0; t8 < 32; ++t8) {
            short8 v = *(const short8*)(rowp + ((t8 * 16) ^ sw));
#pragma unroll
            for (int j = 0; j < 8; ++j) s += bf2f(v[j]);
        }
        skpp[(b * 16 + ch) * 32 + cl] = s;
    }
}

// Reduce partials -> kvbf MFMA-native, sum_kp fp32 (unchanged).
__global__ __launch_bounds__(256) void k_reduce2(
        const float* __restrict__ kvp, const float* __restrict__ skpp,
        short* __restrict__ kvbf, float* __restrict__ sum_kp) {
    int idx = blockIdx.x * 256 + threadIdx.x;
    if (idx < 65536) {
        int b = idx >> 11, rem = idx & 2047, dd = rem >> 5, m = rem & 31;
        float s = 0.f;
        for (int ch = 0; ch < 16; ++ch) s += kvp[((b * 16 + ch) * 64 + dd) * 32 + m];
        int dst = (((b * 2 + (m >> 4)) * 2 + ((m >> 3) & 1)) * 64 + dd) * 8 + (m & 7);
        kvbf[dst] = f2bf(s);
    } else if (idx < 65536 + 1024) {
        int i = idx - 65536;
        int b = i >> 5, m = i & 31;
        float s = 0.f;
        for (int ch = 0; ch < 16; ++ch) s += skpp[(b * 16 + ch) * 32 + m];
        sum_kp[i] = s;
    }
}

// ---------------------------------------------------------------------------
// Fused tail (r12/r16, unchanged).
// ---------------------------------------------------------------------------
__global__ __launch_bounds__(256) void k_fuse(
        const short* __restrict__ vT, const short* __restrict__ qpT,
        const short* __restrict__ kvbf, const float* __restrict__ sum_kp,
        const short* __restrict__ pTbf, const float* __restrict__ proj_b,
        const float* __restrict__ g2, const float* __restrict__ b2ln,
        const short* __restrict__ w1bf, const float* __restrict__ b1,
        const short* __restrict__ w2bf, const float* __restrict__ b2,
        float* __restrict__ out) {
    const int b = blockIdx.y;
    const int t0 = blockIdx.x * 64;
    const int tid = threadIdx.x;
    const int lane = tid & 63;
    const int cl = lane & 31;
    const int g  = lane >> 5;
    const int wv = tid >> 6;
    const int wr = wv & 1;
    const int wc = wv >> 1;

    __shared__ __align__(16) char pool[29952];
    short* qpS  = (short*)(pool + 0);
    short* ytS  = (short*)(pool + 5120);
    short* xnS  = (short*)(pool + 14336);
    short* hgS  = (short*)(pool + 0);
    float* outS = (float*)(pool + 9216);
    float* red  = (float*)(pool + 26624);
    float* stat = (float*)(pool + 27648);
    float* coefS= (float*)(pool + 28672);

    if (tid < 64) {
        coefS[tid]       = proj_b[tid];
        coefS[64 + tid]  = g2[tid];
        coefS[128 + tid] = b2ln[tid];
        coefS[192 + tid] = b1[tid];
        coefS[256 + tid] = b2[tid];
    }
    {
        const int t = tid & 63, q = tid >> 6;
        const float* sk = sum_kp + b * 32;
        float dsum = 0.f;
        short8 pk;
#pragma unroll
        for (int i = 0; i < 8; ++i) {
            int m = q * 8 + i;
            short s = qpT[((size_t)(b * 32 + m)) * TOK + t0 + t];
            dsum = fmaf(bf2f(s), sk[m], dsum);
            pk[i] = s;
        }
        *(short8*)(qpS + t * 40 + q * 8) = pk;
        red[t * 4 + q] = dsum;
    }
    __syncthreads();

    const int tl = wc * 32 + cl;
    const int tg = t0 + tl;
    const int rcol = wr * 32 + cl;

    f32x16 acc = {0.f, 0.f, 0.f, 0.f, 0.f, 0.f, 0.f, 0.f,
                  0.f, 0.f, 0.f, 0.f, 0.f, 0.f, 0.f, 0.f};
    {
        const short* Ab = kvbf + (size_t)b * 2048;
        short8 a0 = *(const short8*)(Ab + (g * 64 + rcol) * 8);
        short8 a1 = *(const short8*)(Ab + ((2 + g) * 64 + rcol) * 8);
        short8 b0 = *(const short8*)(qpS + tl * 40 + g * 8);
        short8 b1v = *(const short8*)(qpS + tl * 40 + 16 + g * 8);
        acc = __builtin_amdgcn_mfma_f32_32x32x16_bf16(a0, b0, acc, 0, 0, 0);
        acc = __builtin_amdgcn_mfma_f32_32x32x16_bf16(a1, b1v, acc, 0, 0, 0);
    }
    {
        float Dv = red[tl * 4 + 0] + red[tl * 4 + 1] + red[tl * 4 + 2] + red[tl * 4 + 3];
        float rD = 1.f / (Dv + 1e-8f);
#pragma unroll
        for (int rq = 0; rq < 4; ++rq) {
            int d0 = wr * 32 + 8 * rq + 4 * g;
            short4v p;
            p.x = f2bf(acc[rq * 4 + 0] * rD);
            p.y = f2bf(acc[rq * 4 + 1] * rD);
            p.z = f2bf(acc[rq * 4 + 2] * rD);
            p.w = f2bf(acc[rq * 4 + 3] * rD);
            *(short4v*)(ytS + tl * 72 + d0) = p;
        }
    }
    __syncthreads();

    f32x16 acc2 = {0.f, 0.f, 0.f, 0.f, 0.f, 0.f, 0.f, 0.f,
                   0.f, 0.f, 0.f, 0.f, 0.f, 0.f, 0.f, 0.f};
    {
#pragma unroll
        for (int ks = 0; ks < 4; ++ks) {
            short8 a = *(const short8*)(pTbf + ((ks * 2 + g) * 64 + rcol) * 8);
            short8 bb = *(const short8*)(ytS + tl * 72 + ks * 16 + g * 8);
            acc2 = __builtin_amdgcn_mfma_f32_32x32x16_bf16(a, bb, acc2, 0, 0, 0);
        }
    }
    float skv[16];
    {
        const short* vb = vT + (size_t)b * 64 * TOK + tg;
#pragma unroll
        for (int reg = 0; reg < 16; ++reg) {
            int o = wr * 32 + (reg & 3) + 8 * (reg >> 2) + 4 * g;
            skv[reg] = acc2[reg] + bf2f(vb[(size_t)o * TOK]) + coefS[o];
        }
    }

    {
        float s1 = 0.f, s2 = 0.f;
#pragma unroll
        for (int reg = 0; reg < 16; ++reg) {
            s1 += skv[reg];
            s2 = fmaf(skv[reg], skv[reg], s2);
        }
        s1 += __shfl_xor(s1, 32, 64);
        s2 += __shfl_xor(s2, 32, 64);
        if (g == 0) {
            stat[(wr * 64 + tl) * 2 + 0] = s1;
            stat[(wr * 64 + tl) * 2 + 1] = s2;
        }
        __syncthreads();
        float S1 = s1 + stat[((wr ^ 1) * 64 + tl) * 2 + 0];
        float S2 = s2 + stat[((wr ^ 1) * 64 + tl) * 2 + 1];
        float mu = S1 * (1.f / 64.f);
        float var = S2 * (1.f / 64.f) - mu * mu;
        float rs = rsqrtf(fmaxf(var, 0.f) + 1e-5f);
#pragma unroll
        for (int rq = 0; rq < 4; ++rq) {
            int o0 = wr * 32 + 8 * rq + 4 * g;
            short4v p;
#pragma unroll
            for (int j = 0; j < 4; ++j) {
                int o = o0 + j;
                float xn = (skv[rq * 4 + j] - mu) * rs * coefS[64 + o] + coefS[128 + o];
                ((short*)&p)[j] = f2bf(xn);
            }
            *(short4v*)(xnS + tl * 72 + o0) = p;
        }
    }
    __syncthreads();

    f32x16 acc3 = {0.f, 0.f, 0.f, 0.f, 0.f, 0.f, 0.f, 0.f,
                   0.f, 0.f, 0.f, 0.f, 0.f, 0.f, 0.f, 0.f};
    {
#pragma unroll
        for (int ks = 0; ks < 4; ++ks) {
            short8 a = *(const short8*)(w1bf + ((ks * 2 + g) * 64 + rcol) * 8);
            short8 bb = *(const short8*)(xnS + tl * 72 + ks * 16 + g * 8);
            acc3 = __builtin_amdgcn_mfma_f32_32x32x16_bf16(a, bb, acc3, 0, 0, 0);
        }
    }
    __syncthreads();
    {
#pragma unroll
        for (int rq = 0; rq < 4; ++rq) {
            int i0 = wr * 32 + 8 * rq + 4 * g;
            short4v p;
#pragma unroll
            for (int j = 0; j < 4; ++j) {
                int i = i0 + j;
                float hgv = gelu_fast(acc3[rq * 4 + j] + coefS[192 + i]);
                ((short*)&p)[j] = f2bf(hgv);
            }
            *(short4v*)(hgS + tl * 72 + i0) = p;
        }
    }
    __syncthreads();

    f32x16 acc4 = {0.f, 0.f, 0.f, 0.f, 0.f, 0.f, 0.f, 0.f,
                   0.f, 0.f, 0.f, 0.f, 0.f, 0.f, 0.f, 0.f};
    {
#pragma unroll
        for (int ks = 0; ks < 4; ++ks) {
            short8 a = *(const short8*)(w2bf + ((ks * 2 + g) * 64 + rcol) * 8);
            short8 bb = *(const short8*)(hgS + tl * 72 + ks * 16 + g * 8);
            acc4 = __builtin_amdgcn_mfma_f32_32x32x16_bf16(a, bb, acc4, 0, 0, 0);
        }
    }
    {
#pragma unroll
        for (int rq = 0; rq < 4; ++rq) {
            int o0 = wr * 32 + 8 * rq + 4 * g;
            float4 f;
#pragma unroll
            for (int j = 0; j < 4; ++j) {
                int o = o0 + j;
                ((float*)&f)[j] = skv[rq * 4 + j] + acc4[rq * 4 + j] + coefS[256 + o];
            }
            *(float4*)(outS + tl * 68 + o0) = f;
        }
    }
    __syncthreads();

    {
        const int tt = tid >> 2, qq = tid & 3;
        float* ob = out + ((size_t)(b * TOK) + t0 + tt) * 64;
#pragma unroll
        for (int it = 0; it < 4; ++it) {
            *(float4*)(ob + it * 16 + qq * 4) =
                *(float4*)(outS + tt * 68 + it * 16 + qq * 4);
        }
    }
}

// ---------------------------------------------------------------------------
extern "C" void kernel_launch(void* const* d_in, const int* in_sizes, int n_in,
                              void* d_out, int out_size, void* d_ws, size_t ws_size,
                              hipStream_t stream) {
    const float* x      = (const float*)d_in[0];
    const float* conv_w = (const float*)d_in[1];
    const float* conv_b = (const float*)d_in[2];
    const float* ln1_g  = (const float*)d_in[3];
    const float* ln1_b  = (const float*)d_in[4];
    const float* kqv_w  = (const float*)d_in[5];
    const float* kqv_b  = (const float*)d_in[6];
    const float* proj_w = (const float*)d_in[7];
    const float* proj_b = (const float*)d_in[8];
    const float* w_perf = (const float*)d_in[9];
    const float* ln2_g  = (const float*)d_in[10];
    const float* ln2_b  = (const float*)d_in[11];
    const float* mlp_w1 = (const float*)d_in[12];
    const float* mlp_b1 = (const float*)d_in[13];
    const float* mlp_w2 = (const float*)d_in[14];
    const float* mlp_b2 = (const float*)d_in[15];

    float* ws = (float*)d_ws;
    short* w2c    = (short*)ws;                 // 110592 sh
    short* kwbf   = (short*)(ws + 55296);       // 36864 sh
    short* pTbf   = (short*)(ws + 73728);       // 4096 sh
    short* w1bf   = (short*)(ws + 75776);       // 4096 sh
    short* w2bf   = (short*)(ws + 77824);       // 4096 sh
    short* wpbf   = (short*)(ws + 79872);       // 2048 sh
    float* sum_kp = ws + 80896;                 // 1024 f
    short* kvbf   = (short*)(ws + 81920);       // 65536 sh -> ends ws+114688
    // tokens bf16 (dead after lnkqvp)
    short* tokens = (short*)(ws + 114688);      // 25165824 sh
    // region B: outputs of lnkqvp (must not alias tokens)
    float* wsB    = ws + 114688 + 12582912;
    short* vT     = (short*)wsB;                // 8388608 sh
    short* qpT    = (short*)(wsB + 4194304);    // 4194304 sh
    short* kpT    = (short*)(wsB + 6291456);    // 4194304 sh
    float* skpp   = wsB + 8388608;              // 16384 f
    float* kvp    = wsB + 8404992;              // 1048576 f
    float* outp   = (float*)d_out;

    k_prep   <<<632, 256, 0, stream>>>(conv_w, kqv_w, proj_w, mlp_w1, mlp_w2,
                                       w_perf, w2c, kwbf, pTbf, w1bf, w2bf, wpbf);
    k_conv6  <<<6144, 256, 0, stream>>>(x, w2c, conv_b, tokens);
    k_lnkqvp <<<dim3(64, 32), 256, 0, stream>>>(tokens, ln1_g, ln1_b, kwbf,
                                                kqv_b, wpbf, vT, kpT, qpT);
    k_kptv   <<<dim3(16, 32), 256, 0, stream>>>(vT, kpT, kvp, skpp);
    k_reduce2<<<260, 256, 0, stream>>>(kvp, skpp, kvbf, sum_kp);
    k_fuse   <<<dim3(64, 32), 256, 0, stream>>>(vT, qpT, kvbf, sum_kp,
                                                pTbf, proj_b, ln2_g, ln2_b,
                                                w1bf, mlp_b1, w2bf, mlp_b2, outp);
}